// Round 3
// baseline (1513.464 us; speedup 1.0000x reference)
//
#include <hip/hip_runtime.h>
#include <math.h>

#define B_   4096

// ---------------------------------------------------------------------------
// prep: W2t[i][f*5+k] = W2[f][i][k]   (row stride 152, contiguous per i)
// ---------------------------------------------------------------------------
__global__ void prep_w2t(const float* __restrict__ W2, float* __restrict__ W2t)
{
    int idx = blockIdx.x * 256 + threadIdx.x;
    if (idx < 9600) {
        int f = idx / 320, r = idx % 320, i = r / 5, k = r % 5;
        W2t[i * 152 + f * 5 + k] = W2[idx];
    }
}

// ---------------------------------------------------------------------------
// Encoders (both in one launch, grid.y selects V/P):
// conv(3->64,K=3) + ReLU + mean. lane = t position (per-lane LDS reads,
// conflict-free), channel loop inner with wave-uniform scalar weights.
// 2 batch elems per block: waves {0,1}->b0, {2,3}->b1.
// NOTE x layout is [T][C]: element (t+k, ch i) = x[3*k+i]; weight W[c][i][k].
// ---------------------------------------------------------------------------
__global__ __launch_bounds__(256, 4) void encode2_kernel(
    const float* __restrict__ S_V, const float* __restrict__ S_P,
    const float* __restrict__ Wc_v, const float* __restrict__ bc_v,
    const float* __restrict__ Wc_p, const float* __restrict__ bc_p,
    float* __restrict__ hv, float* __restrict__ hp)
{
    __shared__ __align__(16) float xs[2][3072];
    __shared__ float part[4][64];
    const int enc = blockIdx.y;
    const float* S  = enc ? S_P  : S_V;
    const float* Wc = enc ? Wc_p : Wc_v;
    const float* bc = enc ? bc_p : bc_v;
    float* hout     = enc ? hp   : hv;

    const int tid  = threadIdx.x;
    const int lane = tid & 63;
    const int wv   = tid >> 6;
    const int bsub = wv >> 1;               // which batch elem of the pair
    const int half = wv & 1;                // which half of the t range

    // stage both signals: 2 x 3072 floats, coalesced float4
    {
        const float4* src = (const float4*)(S + (size_t)blockIdx.x * 2 * 3072);
        float4* dst = (float4*)&xs[0][0];
        for (int i = tid; i < 1536; i += 256) dst[i] = src[i];
    }
    __syncthreads();

    float acc[64];
    #pragma unroll
    for (int c = 0; c < 64; ++c) acc[c] = 0.f;

    const float* x0 = &xs[bsub][0];
    #pragma unroll 1
    for (int it = 0; it < 8; ++it) {
        const int t = half * 64 + lane + 128 * it;
        if (t < 1022) {
            float x[9];
            #pragma unroll
            for (int j = 0; j < 9; ++j) x[j] = x0[3 * t + j];
            #pragma unroll 8
            for (int c = 0; c < 64; ++c) {
                float s = bc[c];               // wave-uniform -> s_load
                #pragma unroll
                for (int i = 0; i < 3; ++i)
                    #pragma unroll
                    for (int k = 0; k < 3; ++k)
                        s = fmaf(Wc[c * 9 + i * 3 + k], x[3 * k + i], s);
                acc[c] += fmaxf(s, 0.f);
            }
        }
    }

    // butterfly-sum each channel across 64 lanes; lane c keeps channel c
    float h = 0.f;
    #pragma unroll
    for (int c = 0; c < 64; ++c) {
        float v = acc[c];
        v += __shfl_xor(v, 1);
        v += __shfl_xor(v, 2);
        v += __shfl_xor(v, 4);
        v += __shfl_xor(v, 8);
        v += __shfl_xor(v, 16);
        v += __shfl_xor(v, 32);
        if (lane == c) h = v;
    }
    part[wv][lane] = h;
    __syncthreads();
    if (tid < 128) {
        const int bs = tid >> 6;
        float hh = (part[bs * 2][lane] + part[bs * 2 + 1][lane]) * (1.0f / 1022.0f);
        hout[(size_t)(blockIdx.x * 2 + bs) * 64 + lane] = hh;
    }
}

// ---------------------------------------------------------------------------
// Physical model: conv(3->64,K=5) -> maxpool4 -> conv(64->30,K=5) -> maxpool4
// -> mean.  Phase 1: lane = pooled position tp, channel loop inner (scalar
// weights), conflict-free p1 writes (stride 261). Phase 2: lane = t2, W2t
// contiguous scalar loads, acc[30] in VGPRs, shuffle pool+mean.
// ---------------------------------------------------------------------------
#define P1S 261
__global__ __launch_bounds__(256, 2) void phys_kernel(
    const float* __restrict__ S, const float* __restrict__ W1,
    const float* __restrict__ b1, const float* __restrict__ W2t,
    const float* __restrict__ b2, float* __restrict__ y30)
{
    __shared__ __align__(16) float xs[3072];
    __shared__ __align__(16) float p1[64 * P1S];
    __shared__ float ypart[4][32];
    const int b = blockIdx.x;
    const int tid = threadIdx.x;
    const int lane = tid & 63;
    const int wv = tid >> 6;

    {
        const float4* src = (const float4*)(S + (size_t)b * 3072);
        float4* dst = (float4*)xs;
        for (int i = tid; i < 768; i += 256) dst[i] = src[i];
    }
    // zero pad columns tp = 255..260
    for (int i = tid; i < 64 * 6; i += 256) {
        int r = i / 6, c = 255 + (i % 6);
        p1[r * P1S + c] = 0.f;
    }
    __syncthreads();

    // ---- phase 1: lane = tp in 0..254
    const int tp = tid;
    if (tp < 255) {
        float x[24];                        // positions 4tp..4tp+7, 3 ch each
        #pragma unroll
        for (int j = 0; j < 24; ++j) x[j] = xs[12 * tp + j];
        #pragma unroll 4
        for (int c = 0; c < 64; ++c) {
            float m = -INFINITY;
            #pragma unroll
            for (int p = 0; p < 4; ++p) {
                float s = 0.f;
                #pragma unroll
                for (int i = 0; i < 3; ++i)
                    #pragma unroll
                    for (int k = 0; k < 5; ++k)
                        s = fmaf(W1[c * 15 + i * 5 + k], x[3 * (p + k) + i], s);
                m = fmaxf(m, s);
            }
            p1[c * P1S + tp] = m + b1[c];   // consecutive lanes -> no conflict
        }
    }
    __syncthreads();

    // ---- phase 2: conv2 at t2 = tid, 30 output channels in VGPRs
    float acc[30];
    #pragma unroll
    for (int f = 0; f < 30; ++f) acc[f] = 0.f;
    const int t2 = tid;
    #pragma unroll 1
    for (int i = 0; i < 64; ++i) {
        const float* pr = p1 + i * P1S + t2;
        float x0 = pr[0], x1 = pr[1], x2 = pr[2], x3 = pr[3], x4 = pr[4];
        const float* wp = W2t + i * 152;    // contiguous 150 floats -> s_load
        #pragma unroll
        for (int f = 0; f < 30; ++f) {
            const float* wf = wp + f * 5;
            float a = acc[f];
            a = fmaf(wf[0], x0, a);
            a = fmaf(wf[1], x1, a);
            a = fmaf(wf[2], x2, a);
            a = fmaf(wf[3], x3, a);
            a = fmaf(wf[4], x4, a);
            acc[f] = a;
        }
    }
    // ---- maxpool4 over t2 (62 windows, t2 0..247) + mean
    const bool valid = (t2 < 248);
    #pragma unroll 1
    for (int f = 0; f < 30; ++f) {
        float v = acc[f];
        v = fmaxf(v, __shfl_xor(v, 1));
        v = fmaxf(v, __shfl_xor(v, 2));
        v = ((lane & 3) == 0 && valid) ? v : 0.f;
        v += __shfl_xor(v, 4);
        v += __shfl_xor(v, 8);
        v += __shfl_xor(v, 16);
        v += __shfl_xor(v, 32);
        if (lane == 0) ypart[wv][f] = v;
    }
    __syncthreads();
    if (tid < 30) {
        float y = (ypart[0][tid] + ypart[1][tid] +
                   ypart[2][tid] + ypart[3][tid]) * (1.0f / 62.0f) + b2[tid];
        y30[(size_t)b * 30 + tid] = y;
    }
}

// ---------------------------------------------------------------------------
// Heads + LSE soft-OR fusion + masked 4-token attention. 1 wave per b.
// ---------------------------------------------------------------------------
__global__ __launch_bounds__(64) void head_kernel(
    const int* __restrict__ pairs,
    const float* __restrict__ hv_g, const float* __restrict__ hp_g,
    const float* __restrict__ y30_g,
    const float* __restrict__ Ws_v, const float* __restrict__ bs_v,
    const float* __restrict__ Wd_v, const float* __restrict__ bd_v,
    const float* __restrict__ Ws_p, const float* __restrict__ bs_p,
    const float* __restrict__ Wd_p, const float* __restrict__ bd_p,
    const float* __restrict__ Wsp, const float* __restrict__ bsp,
    const float* __restrict__ Wa,  const float* __restrict__ ba,
    const float* __restrict__ Wf,  const float* __restrict__ bf,
    float* __restrict__ out)
{
    __shared__ float hv[64], hp[64];
    __shared__ float s0v[32], s0p[32];
    __shared__ float f4[4][32];
    __shared__ float qk[4][192];
    __shared__ float qm[32];
    __shared__ float lg[4][4];
    __shared__ float wsm[4][4];
    __shared__ float ffl[4][32];
    const int b = blockIdx.x;
    const int lane = threadIdx.x;
    const int pf = pairs[b];

    hv[lane] = hv_g[(size_t)b * 64 + lane];
    hp[lane] = hp_g[(size_t)b * 64 + lane];
    __syncthreads();

    if (lane < 30) {
        float a_s = bs_v[lane], a_d = bd_v[lane];
        float p_s = bs_p[lane], p_d = bd_p[lane];
        for (int k = 0; k < 64; ++k) {
            float h = hv[k], g = hp[k];
            a_s = fmaf(h, Ws_v[k*30 + lane], a_s);
            a_d = fmaf(h, Wd_v[k*30 + lane], a_d);
            p_s = fmaf(g, Ws_p[k*30 + lane], p_s);
            p_d = fmaf(g, Wd_p[k*30 + lane], p_d);
        }
        s0v[lane] = a_s;
        s0p[lane] = p_s;
        f4[3][lane] = a_d;
        f4[0][lane] = p_d;
        f4[2][lane] = y30_g[(size_t)b * 30 + lane];
    }
    __syncthreads();

    if (lane < 30) {
        float v_s = bsp[lane], p_s = bsp[lane];
        for (int j = 0; j < 30; ++j) {
            float wj = Wsp[j*30 + lane];
            v_s = fmaf(s0v[j], wj, v_s);
            p_s = fmaf(s0p[j], wj, p_s);
        }
        float h1 = v_s, h2 = p_s, h12 = h1 + h2;
        float m1 = fmaxf(h12, fmaxf(h1, h2));
        float lse1 = m1 + logf(2.f*expf(h12 - m1) + expf(h1 - m1) + expf(h2 - m1));
        float m2 = fmaxf(0.f, fmaxf(h1, h2));
        float lse2 = m2 + logf(2.f*expf(-m2) + expf(h1 - m2) + expf(h2 - m2));
        f4[1][lane] = pf ? (lse1 - lse2) : h2;
    }
    __syncthreads();

    #pragma unroll 1
    for (int t = 0; t < 4; ++t) {
        #pragma unroll 1
        for (int c0 = 0; c0 < 3; ++c0) {
            int c = c0 * 64 + lane;
            float a = ba[c];
            for (int j = 0; j < 30; ++j)
                a = fmaf(f4[t][j], Wa[j*192 + c], a);
            qk[t][c] = a;
        }
    }
    __syncthreads();

    if (lane < 32) {
        float q0 = qk[0][lane], q1 = qk[1][lane], q2 = qk[2][lane], q3 = qk[3][lane];
        qm[lane] = pf ? (q0 + q1 + q2 + q3) * 0.25f
                      : (q0 + q1 + q2) * (1.f / 3.f);
    }
    __syncthreads();

    if (lane < 16) {
        int n = lane >> 2, t = lane & 3;
        float a = 0.f;
        const float* kp = &qk[t][64 + 32*n];
        for (int d = 0; d < 32; ++d) a = fmaf(kp[d], qm[d], a);
        a *= 0.17677669529663687f;
        if (t == 3 && pf == 0) a = -INFINITY;
        lg[n][t] = a;
    }
    __syncthreads();

    if (lane < 4) {
        float l0 = lg[lane][0], l1 = lg[lane][1], l2 = lg[lane][2], l3 = lg[lane][3];
        float m = fmaxf(fmaxf(l0, l1), fmaxf(l2, l3));
        float e0 = expf(l0 - m), e1 = expf(l1 - m), e2 = expf(l2 - m);
        float e3 = expf(l3 - m);
        float s = e0 + e1 + e2 + e3;
        wsm[lane][0] = e0 / s; wsm[lane][1] = e1 / s;
        wsm[lane][2] = e2 / s; wsm[lane][3] = e3 / s;
    }
    __syncthreads();

    #pragma unroll
    for (int r = 0; r < 2; ++r) {
        int n = (lane >> 5) + 2 * r, d = lane & 31;
        float a = 0.f;
        #pragma unroll
        for (int t = 0; t < 4; ++t) a = fmaf(wsm[n][t], qk[t][32 + d], a);
        ffl[n][d] = a;
    }
    __syncthreads();

    if (lane < 4) {
        float a = bf[lane];
        for (int d = 0; d < 32; ++d) a = fmaf(ffl[lane][d], Wf[d*4 + lane], a);
        out[(size_t)b * 4 + lane] = a;
    }
}

// ---------------------------------------------------------------------------
extern "C" void kernel_launch(void* const* d_in, const int* in_sizes, int n_in,
                              void* d_out, int out_size, void* d_ws, size_t ws_size,
                              hipStream_t stream)
{
    const int*   pairs = (const int*)  d_in[0];
    const float* S_V   = (const float*)d_in[1];
    const float* S_P   = (const float*)d_in[2];
    const float* S_P1  = (const float*)d_in[3];
    const float* Wc_v  = (const float*)d_in[4];
    const float* bc_v  = (const float*)d_in[5];
    const float* Ws_v  = (const float*)d_in[6];
    const float* bs_v  = (const float*)d_in[7];
    const float* Wd_v  = (const float*)d_in[8];
    const float* bd_v  = (const float*)d_in[9];
    const float* Wc_p  = (const float*)d_in[10];
    const float* bc_p  = (const float*)d_in[11];
    const float* Ws_p  = (const float*)d_in[12];
    const float* bs_p  = (const float*)d_in[13];
    const float* Wd_p  = (const float*)d_in[14];
    const float* bd_p  = (const float*)d_in[15];
    const float* Wsp   = (const float*)d_in[16];
    const float* bsp   = (const float*)d_in[17];
    const float* W1    = (const float*)d_in[18];
    const float* b1    = (const float*)d_in[19];
    const float* W2    = (const float*)d_in[20];
    const float* b2    = (const float*)d_in[21];
    const float* Wa    = (const float*)d_in[22];
    const float* ba    = (const float*)d_in[23];
    const float* Wf    = (const float*)d_in[24];
    const float* bf    = (const float*)d_in[25];
    float* out = (float*)d_out;

    // workspace: h_v[B][64] | h_p[B][64] | y30[B][30] | W2t[64][152]
    float* ws  = (float*)d_ws;
    float* h_v = ws;
    float* h_p = ws + (size_t)B_ * 64;
    float* y30 = ws + (size_t)2 * B_ * 64;
    float* W2t = ws + (size_t)2 * B_ * 64 + (size_t)B_ * 30;

    prep_w2t<<<(9600 + 255) / 256, 256, 0, stream>>>(W2, W2t);
    encode2_kernel<<<dim3(B_ / 2, 2), 256, 0, stream>>>(
        S_V, S_P, Wc_v, bc_v, Wc_p, bc_p, h_v, h_p);
    phys_kernel<<<B_, 256, 0, stream>>>(S_P1, W1, b1, W2t, b2, y30);
    head_kernel<<<B_, 64, 0, stream>>>(pairs, h_v, h_p, y30,
                                       Ws_v, bs_v, Wd_v, bd_v,
                                       Ws_p, bs_p, Wd_p, bd_p,
                                       Wsp, bsp, Wa, ba, Wf, bf, out);
}

// Round 4
// 474.397 us; speedup vs baseline: 3.1903x; 3.1903x over previous
//
#include <hip/hip_runtime.h>
#include <math.h>

#define B_   4096

typedef __attribute__((ext_vector_type(8))) short bf16x8;   // 8 bf16 = 4 VGPR
typedef __attribute__((ext_vector_type(4))) float f32x4;

__device__ __forceinline__ unsigned short f2bf(float f) {   // RNE f32->bf16
    unsigned int u = __float_as_uint(f);
    u += 0x7FFFu + ((u >> 16) & 1u);
    return (unsigned short)(u >> 16);
}

// ---------------------------------------------------------------------------
// prep: A-fragments of W2 for 16x16x32 bf16 MFMA, 5 shifted GEMMs (one per kk).
// Entry e = (kk*2 + Ks)*2 + ftile, lane in [0,64): 8 bf16 =
//   A[m = lane&15][k = (lane>>4)*8 + j] with f = ftile*16+m (0 if f>=30),
//   i = Ks*32 + (lane>>4)*8 + j, value = W2[f][i][kk]  (W2 flat f*320+i*5+kk)
// ---------------------------------------------------------------------------
__global__ void prep_afrag(const float* __restrict__ W2,
                           unsigned short* __restrict__ Afrag)
{
    int gid = blockIdx.x * 256 + threadIdx.x;
    if (gid >= 1280) return;
    int lane = gid & 63, e = gid >> 6;
    int ft = e & 1, Ks = (e >> 1) & 1, kk = e >> 2;
    int m = lane & 15, kg = lane >> 4;
    int f = ft * 16 + m;
    unsigned int w[4];
    #pragma unroll
    for (int p = 0; p < 4; ++p) {
        int i0 = Ks * 32 + kg * 8 + 2 * p;
        float v0 = (f < 30) ? W2[f * 320 + i0 * 5 + kk] : 0.f;
        float v1 = (f < 30) ? W2[f * 320 + (i0 + 1) * 5 + kk] : 0.f;
        w[p] = (unsigned int)f2bf(v0) | ((unsigned int)f2bf(v1) << 16);
    }
    ((uint4*)Afrag)[gid] = make_uint4(w[0], w[1], w[2], w[3]);
}

// ---------------------------------------------------------------------------
// Encoders (both in one launch, grid.y selects V/P):
// conv(3->64,K=3) + ReLU + mean. lane = t position, channel loop FULLY
// unrolled so acc[64] is statically indexed -> stays in VGPRs (R3's
// "#pragma unroll 8" left it runtime-indexed -> 2.3 GB of scratch spill).
// x layout [T][C]: element (t+k, ch i) = x[3*k+i]; weight W[c][i][k].
// ---------------------------------------------------------------------------
__global__ __launch_bounds__(256, 4) void encode2_kernel(
    const float* __restrict__ S_V, const float* __restrict__ S_P,
    const float* __restrict__ Wc_v, const float* __restrict__ bc_v,
    const float* __restrict__ Wc_p, const float* __restrict__ bc_p,
    float* __restrict__ hv, float* __restrict__ hp)
{
    __shared__ __align__(16) float xs[2][3072];
    __shared__ float part[4][64];
    const int enc = blockIdx.y;
    const float* S  = enc ? S_P  : S_V;
    const float* Wc = enc ? Wc_p : Wc_v;
    const float* bc = enc ? bc_p : bc_v;
    float* hout     = enc ? hp   : hv;

    const int tid  = threadIdx.x;
    const int lane = tid & 63;
    const int wv   = tid >> 6;
    const int bsub = wv >> 1;
    const int half = wv & 1;

    {
        const float4* src = (const float4*)(S + (size_t)blockIdx.x * 2 * 3072);
        float4* dst = (float4*)&xs[0][0];
        for (int i = tid; i < 1536; i += 256) dst[i] = src[i];
    }
    __syncthreads();

    float acc[64];
    #pragma unroll
    for (int c = 0; c < 64; ++c) acc[c] = 0.f;

    const float* x0 = &xs[bsub][0];
    #pragma unroll 1
    for (int it = 0; it < 8; ++it) {
        const int t = half * 64 + lane + 128 * it;
        if (t < 1022) {
            float x[9];
            #pragma unroll
            for (int j = 0; j < 9; ++j) x[j] = x0[3 * t + j];
            #pragma unroll                      // FULL unroll: static acc idx
            for (int c = 0; c < 64; ++c) {
                float s = bc[c];
                #pragma unroll
                for (int i = 0; i < 3; ++i)
                    #pragma unroll
                    for (int k = 0; k < 3; ++k)
                        s = fmaf(Wc[c * 9 + i * 3 + k], x[3 * k + i], s);
                acc[c] += fmaxf(s, 0.f);
            }
        }
    }

    float h = 0.f;
    #pragma unroll
    for (int c = 0; c < 64; ++c) {
        float v = acc[c];
        v += __shfl_xor(v, 1);
        v += __shfl_xor(v, 2);
        v += __shfl_xor(v, 4);
        v += __shfl_xor(v, 8);
        v += __shfl_xor(v, 16);
        v += __shfl_xor(v, 32);
        if (lane == c) h = v;
    }
    part[wv][lane] = h;
    __syncthreads();
    if (tid < 128) {
        const int bs = tid >> 6;
        float hh = (part[bs * 2][lane] + part[bs * 2 + 1][lane]) * (1.0f / 1022.0f);
        hout[(size_t)(blockIdx.x * 2 + bs) * 64 + lane] = hh;
    }
}

// ---------------------------------------------------------------------------
// Physical model: conv(3->64,K=5) -> maxpool4 -> conv(64->30,K=5) -> maxpool4
// -> mean.
// Phase 1 (fp32 VALU): lane = pooled position tp, conv1+maxpool -> bf16
//   p1T[t][i] (transposed, row stride 72 bf16 for LDS bank spread).
// Phase 2 (bf16 MFMA): y[f,n] = sum_kk sum_i W2[f,i,kk]*p1T[n+kk][i] as 5
//   shifted GEMMs, 16x16x32 MFMA. B-frag = one ds_read_b128 (8 contiguous i).
//   A-frags preloaded from global (prep_afrag). Pool4+mean via shuffles.
// ---------------------------------------------------------------------------
#define P1TS 72
__global__ __launch_bounds__(256, 3) void phys_kernel(
    const float* __restrict__ S, const float* __restrict__ W1,
    const float* __restrict__ b1, const unsigned short* __restrict__ Afrag,
    const float* __restrict__ b2, float* __restrict__ y30)
{
    __shared__ __align__(16) float xs[3072];
    __shared__ __align__(16) unsigned short p1T[260 * P1TS];
    __shared__ float ypartL[4][32];
    const int b = blockIdx.x;
    const int tid = threadIdx.x;
    const int lane = tid & 63;
    const int wv = tid >> 6;

    {
        const float4* src = (const float4*)(S + (size_t)b * 3072);
        float4* dst = (float4*)xs;
        for (int i = tid; i < 768; i += 256) dst[i] = src[i];
    }
    // zero rows 255..259 (read via kk shifts): 5*72 ushorts = 180 dwords
    if (tid < 180) ((unsigned int*)(p1T + 255 * P1TS))[tid] = 0u;

    // preload all 20 A-fragments early (hidden behind phase 1 compute)
    bf16x8 Af[20];
    {
        const bf16x8* ag = (const bf16x8*)Afrag;
        #pragma unroll
        for (int e = 0; e < 20; ++e) Af[e] = ag[e * 64 + lane];
    }
    __syncthreads();

    // ---- phase 1: lane = tp in 0..254, write p1T[tp][c] as packed bf16 pairs
    const int tp = tid;
    if (tp < 255) {
        float x[24];
        #pragma unroll
        for (int j = 0; j < 24; ++j) x[j] = xs[12 * tp + j];
        #pragma unroll 1
        for (int c = 0; c < 64; c += 2) {
            float mm[2];
            #pragma unroll
            for (int hh = 0; hh < 2; ++hh) {
                const float* w = W1 + (c + hh) * 15;    // wave-uniform
                float m = -INFINITY;
                #pragma unroll
                for (int p = 0; p < 4; ++p) {
                    float s = 0.f;
                    #pragma unroll
                    for (int i = 0; i < 3; ++i)
                        #pragma unroll
                        for (int k = 0; k < 5; ++k)
                            s = fmaf(w[i * 5 + k], x[3 * (p + k) + i], s);
                    m = fmaxf(m, s);
                }
                mm[hh] = m + b1[c + hh];
            }
            unsigned int pack = (unsigned int)f2bf(mm[0]) |
                                ((unsigned int)f2bf(mm[1]) << 16);
            *(unsigned int*)(p1T + tp * P1TS + c) = pack;
        }
    }
    __syncthreads();

    // ---- phase 2: MFMA K-loop. wave wv owns ntiles wv*4..wv*4+3.
    const int m_ = lane & 15, kg = lane >> 4;
    f32x4 acc[4][2];
    #pragma unroll
    for (int q = 0; q < 4; ++q) {
        acc[q][0] = (f32x4){0.f, 0.f, 0.f, 0.f};
        acc[q][1] = (f32x4){0.f, 0.f, 0.f, 0.f};
    }
    #pragma unroll
    for (int kk = 0; kk < 5; ++kk) {
        #pragma unroll
        for (int Ks = 0; Ks < 2; ++Ks) {
            const int e0 = (kk * 2 + Ks) * 2;
            #pragma unroll
            for (int q = 0; q < 4; ++q) {
                const int row = wv * 64 + q * 16 + m_ + kk;     // n + kk
                const bf16x8 Bf = *(const bf16x8*)(p1T + row * P1TS + Ks * 32 + kg * 8);
                acc[q][0] = __builtin_amdgcn_mfma_f32_16x16x32_bf16(
                    Af[e0], Bf, acc[q][0], 0, 0, 0);
                acc[q][1] = __builtin_amdgcn_mfma_f32_16x16x32_bf16(
                    Af[e0 + 1], Bf, acc[q][1], 0, 0, 0);
            }
        }
    }

    // ---- epilogue: maxpool4 over n (62 valid windows, n<248), sum, mean
    // C/D layout: f_local = kg*4 + reg, n = ntile*16 + m_
    float ysum[2][4];
    #pragma unroll
    for (int t = 0; t < 2; ++t)
        #pragma unroll
        for (int r = 0; r < 4; ++r) ysum[t][r] = 0.f;

    #pragma unroll
    for (int q = 0; q < 4; ++q) {
        const int n0 = wv * 64 + q * 16 + m_;
        #pragma unroll
        for (int t = 0; t < 2; ++t) {
            #pragma unroll
            for (int r = 0; r < 4; ++r) {
                float v = acc[q][t][r];
                v = fmaxf(v, __shfl_xor(v, 1));
                v = fmaxf(v, __shfl_xor(v, 2));
                v = (((m_ & 3) == 0) && (n0 < 248)) ? v : 0.f;
                v += __shfl_xor(v, 4);
                v += __shfl_xor(v, 8);
                ysum[t][r] += v;
            }
        }
    }
    if (m_ == 0) {
        #pragma unroll
        for (int t = 0; t < 2; ++t)
            #pragma unroll
            for (int r = 0; r < 4; ++r)
                ypartL[wv][t * 16 + kg * 4 + r] = ysum[t][r];
    }
    __syncthreads();
    if (tid < 30) {
        float y = (ypartL[0][tid] + ypartL[1][tid] +
                   ypartL[2][tid] + ypartL[3][tid]) * (1.0f / 62.0f) + b2[tid];
        y30[(size_t)b * 30 + tid] = y;
    }
}

// ---------------------------------------------------------------------------
// Heads + LSE soft-OR fusion + masked 4-token attention. 1 wave per b.
// ---------------------------------------------------------------------------
__global__ __launch_bounds__(64) void head_kernel(
    const int* __restrict__ pairs,
    const float* __restrict__ hv_g, const float* __restrict__ hp_g,
    const float* __restrict__ y30_g,
    const float* __restrict__ Ws_v, const float* __restrict__ bs_v,
    const float* __restrict__ Wd_v, const float* __restrict__ bd_v,
    const float* __restrict__ Ws_p, const float* __restrict__ bs_p,
    const float* __restrict__ Wd_p, const float* __restrict__ bd_p,
    const float* __restrict__ Wsp, const float* __restrict__ bsp,
    const float* __restrict__ Wa,  const float* __restrict__ ba,
    const float* __restrict__ Wf,  const float* __restrict__ bf,
    float* __restrict__ out)
{
    __shared__ float hv[64], hp[64];
    __shared__ float s0v[32], s0p[32];
    __shared__ float f4[4][32];
    __shared__ float qk[4][192];
    __shared__ float qm[32];
    __shared__ float lg[4][4];
    __shared__ float wsm[4][4];
    __shared__ float ffl[4][32];
    const int b = blockIdx.x;
    const int lane = threadIdx.x;
    const int pf = pairs[b];

    hv[lane] = hv_g[(size_t)b * 64 + lane];
    hp[lane] = hp_g[(size_t)b * 64 + lane];
    __syncthreads();

    if (lane < 30) {
        float a_s = bs_v[lane], a_d = bd_v[lane];
        float p_s = bs_p[lane], p_d = bd_p[lane];
        for (int k = 0; k < 64; ++k) {
            float h = hv[k], g = hp[k];
            a_s = fmaf(h, Ws_v[k*30 + lane], a_s);
            a_d = fmaf(h, Wd_v[k*30 + lane], a_d);
            p_s = fmaf(g, Ws_p[k*30 + lane], p_s);
            p_d = fmaf(g, Wd_p[k*30 + lane], p_d);
        }
        s0v[lane] = a_s;
        s0p[lane] = p_s;
        f4[3][lane] = a_d;
        f4[0][lane] = p_d;
        f4[2][lane] = y30_g[(size_t)b * 30 + lane];
    }
    __syncthreads();

    if (lane < 30) {
        float v_s = bsp[lane], p_s = bsp[lane];
        for (int j = 0; j < 30; ++j) {
            float wj = Wsp[j*30 + lane];
            v_s = fmaf(s0v[j], wj, v_s);
            p_s = fmaf(s0p[j], wj, p_s);
        }
        float h1 = v_s, h2 = p_s, h12 = h1 + h2;
        float m1 = fmaxf(h12, fmaxf(h1, h2));
        float lse1 = m1 + logf(2.f*expf(h12 - m1) + expf(h1 - m1) + expf(h2 - m1));
        float m2 = fmaxf(0.f, fmaxf(h1, h2));
        float lse2 = m2 + logf(2.f*expf(-m2) + expf(h1 - m2) + expf(h2 - m2));
        f4[1][lane] = pf ? (lse1 - lse2) : h2;
    }
    __syncthreads();

    #pragma unroll 1
    for (int t = 0; t < 4; ++t) {
        #pragma unroll 1
        for (int c0 = 0; c0 < 3; ++c0) {
            int c = c0 * 64 + lane;
            float a = ba[c];
            for (int j = 0; j < 30; ++j)
                a = fmaf(f4[t][j], Wa[j*192 + c], a);
            qk[t][c] = a;
        }
    }
    __syncthreads();

    if (lane < 32) {
        float q0 = qk[0][lane], q1 = qk[1][lane], q2 = qk[2][lane], q3 = qk[3][lane];
        qm[lane] = pf ? (q0 + q1 + q2 + q3) * 0.25f
                      : (q0 + q1 + q2) * (1.f / 3.f);
    }
    __syncthreads();

    if (lane < 16) {
        int n = lane >> 2, t = lane & 3;
        float a = 0.f;
        const float* kp = &qk[t][64 + 32*n];
        for (int d = 0; d < 32; ++d) a = fmaf(kp[d], qm[d], a);
        a *= 0.17677669529663687f;
        if (t == 3 && pf == 0) a = -INFINITY;
        lg[n][t] = a;
    }
    __syncthreads();

    if (lane < 4) {
        float l0 = lg[lane][0], l1 = lg[lane][1], l2 = lg[lane][2], l3 = lg[lane][3];
        float m = fmaxf(fmaxf(l0, l1), fmaxf(l2, l3));
        float e0 = expf(l0 - m), e1 = expf(l1 - m), e2 = expf(l2 - m);
        float e3 = expf(l3 - m);
        float s = e0 + e1 + e2 + e3;
        wsm[lane][0] = e0 / s; wsm[lane][1] = e1 / s;
        wsm[lane][2] = e2 / s; wsm[lane][3] = e3 / s;
    }
    __syncthreads();

    #pragma unroll
    for (int r = 0; r < 2; ++r) {
        int n = (lane >> 5) + 2 * r, d = lane & 31;
        float a = 0.f;
        #pragma unroll
        for (int t = 0; t < 4; ++t) a = fmaf(wsm[n][t], qk[t][32 + d], a);
        ffl[n][d] = a;
    }
    __syncthreads();

    if (lane < 4) {
        float a = bf[lane];
        for (int d = 0; d < 32; ++d) a = fmaf(ffl[lane][d], Wf[d*4 + lane], a);
        out[(size_t)b * 4 + lane] = a;
    }
}

// ---------------------------------------------------------------------------
extern "C" void kernel_launch(void* const* d_in, const int* in_sizes, int n_in,
                              void* d_out, int out_size, void* d_ws, size_t ws_size,
                              hipStream_t stream)
{
    const int*   pairs = (const int*)  d_in[0];
    const float* S_V   = (const float*)d_in[1];
    const float* S_P   = (const float*)d_in[2];
    const float* S_P1  = (const float*)d_in[3];
    const float* Wc_v  = (const float*)d_in[4];
    const float* bc_v  = (const float*)d_in[5];
    const float* Ws_v  = (const float*)d_in[6];
    const float* bs_v  = (const float*)d_in[7];
    const float* Wd_v  = (const float*)d_in[8];
    const float* bd_v  = (const float*)d_in[9];
    const float* Wc_p  = (const float*)d_in[10];
    const float* bc_p  = (const float*)d_in[11];
    const float* Ws_p  = (const float*)d_in[12];
    const float* bs_p  = (const float*)d_in[13];
    const float* Wd_p  = (const float*)d_in[14];
    const float* bd_p  = (const float*)d_in[15];
    const float* Wsp   = (const float*)d_in[16];
    const float* bsp   = (const float*)d_in[17];
    const float* W1    = (const float*)d_in[18];
    const float* b1    = (const float*)d_in[19];
    const float* W2    = (const float*)d_in[20];
    const float* b2    = (const float*)d_in[21];
    const float* Wa    = (const float*)d_in[22];
    const float* ba    = (const float*)d_in[23];
    const float* Wf    = (const float*)d_in[24];
    const float* bf    = (const float*)d_in[25];
    float* out = (float*)d_out;

    // ws: h_v[B][64] | h_p[B][64] | y30[B][30] | Afrag (20 frags x 64 x 16B)
    float* ws  = (float*)d_ws;
    float* h_v = ws;
    float* h_p = ws + (size_t)B_ * 64;
    float* y30 = ws + (size_t)2 * B_ * 64;
    unsigned short* Afrag = (unsigned short*)(ws + (size_t)2 * B_ * 64 + (size_t)B_ * 30);

    prep_afrag<<<5, 256, 0, stream>>>(W2, Afrag);
    encode2_kernel<<<dim3(B_ / 2, 2), 256, 0, stream>>>(
        S_V, S_P, Wc_v, bc_v, Wc_p, bc_p, h_v, h_p);
    phys_kernel<<<B_, 256, 0, stream>>>(S_P1, W1, b1, Afrag, b2, y30);
    head_kernel<<<B_, 64, 0, stream>>>(pairs, h_v, h_p, y30,
                                       Ws_v, bs_v, Wd_v, bd_v,
                                       Ws_p, bs_p, Wd_p, bd_p,
                                       Wsp, bsp, Wa, ba, Wf, bf, out);
}

// Round 5
// 467.623 us; speedup vs baseline: 3.2365x; 1.0145x over previous
//
#include <hip/hip_runtime.h>
#include <math.h>

#define B_   4096

typedef __attribute__((ext_vector_type(8)))  short bf16x8;   // 8 bf16 = 4 VGPR
typedef __attribute__((ext_vector_type(4)))  float f32x4;
typedef __attribute__((ext_vector_type(16))) float f32x16;

__device__ __forceinline__ unsigned short f2bf(float f) {   // RNE f32->bf16
    unsigned int u = __float_as_uint(f);
    u += 0x7FFFu + ((u >> 16) & 1u);
    return (unsigned short)(u >> 16);
}
__device__ __forceinline__ unsigned int pk2(float a, float b) {
    return (unsigned int)f2bf(a) | ((unsigned int)f2bf(b) << 16);
}

// ---------------------------------------------------------------------------
// prep: all MFMA A-fragments into ws_frag (26 entries x 64 lanes x 16B).
//  e 0..19 : phys phase-2 (16x16x32), e=(kk*2+Ks)*2+ftile (as R4)
//  e 20..23: encoder conv  (32x32x16), e-20 = enc*2+mt
//            A[m=lane&31][k=(lane>>5)*8+j], c=mt*32+m, jj<9 ? Wc[c][jj%3][jj/3]
//  e 24..25: phys phase-1  (32x32x16), mt=e-24, jj<15 ? W1[c][jj%3][jj/3]
// ---------------------------------------------------------------------------
__global__ void prep_frags(const float* __restrict__ W2,
                           const float* __restrict__ Wc_v,
                           const float* __restrict__ Wc_p,
                           const float* __restrict__ W1,
                           unsigned short* __restrict__ ws_frag)
{
    int gid = blockIdx.x * 256 + threadIdx.x;
    if (gid >= 26 * 64) return;
    int lane = gid & 63, e = gid >> 6;
    unsigned int w[4];
    if (e < 20) {
        int ft = e & 1, Ks = (e >> 1) & 1, kk = e >> 2;
        int m = lane & 15, kg = lane >> 4;
        int f = ft * 16 + m;
        #pragma unroll
        for (int p = 0; p < 4; ++p) {
            int i0 = Ks * 32 + kg * 8 + 2 * p;
            float v0 = (f < 30) ? W2[f * 320 + i0 * 5 + kk] : 0.f;
            float v1 = (f < 30) ? W2[f * 320 + (i0 + 1) * 5 + kk] : 0.f;
            w[p] = pk2(v0, v1);
        }
    } else if (e < 24) {
        int e2 = e - 20, enc = e2 >> 1, mt = e2 & 1;
        const float* Wc = enc ? Wc_p : Wc_v;
        int c = mt * 32 + (lane & 31), kg = lane >> 5;
        #pragma unroll
        for (int p = 0; p < 4; ++p) {
            int j0 = kg * 8 + 2 * p, j1 = j0 + 1;
            float v0 = (j0 < 9) ? Wc[c * 9 + (j0 % 3) * 3 + (j0 / 3)] : 0.f;
            float v1 = (j1 < 9) ? Wc[c * 9 + (j1 % 3) * 3 + (j1 / 3)] : 0.f;
            w[p] = pk2(v0, v1);
        }
    } else {
        int mt = e - 24;
        int c = mt * 32 + (lane & 31), kg = lane >> 5;
        #pragma unroll
        for (int p = 0; p < 4; ++p) {
            int j0 = kg * 8 + 2 * p, j1 = j0 + 1;
            float v0 = (j0 < 15) ? W1[c * 15 + (j0 % 3) * 5 + (j0 / 3)] : 0.f;
            float v1 = (j1 < 15) ? W1[c * 15 + (j1 % 3) * 5 + (j1 / 3)] : 0.f;
            w[p] = pk2(v0, v1);
        }
    }
    ((uint4*)ws_frag)[gid] = make_uint4(w[0], w[1], w[2], w[3]);
}

// ---------------------------------------------------------------------------
// Encoder via MFMA: y[c,t] = sum_{jj<9} W'[c][jj] x[3t+jj]; relu; mean_t.
// rows[t][16 halfs] = bf16(x[3t..3t+8]) + zero pad (t>=1022 all-zero).
// One 32x32x16 MFMA per (m-tile, n-tile); bias in C operand; the two zero
// rows contribute exactly relu(bias) each -> subtracted at the end.
// ---------------------------------------------------------------------------
__global__ __launch_bounds__(256, 3) void encode_mfma_kernel(
    const float* __restrict__ S_V, const float* __restrict__ S_P,
    const unsigned short* __restrict__ Frag,
    const float* __restrict__ bc_v, const float* __restrict__ bc_p,
    float* __restrict__ hv, float* __restrict__ hp)
{
    __shared__ __align__(16) float xs[3072];
    __shared__ __align__(16) unsigned short rows[1024 * 16];
    __shared__ float bcs[64];
    __shared__ float hpart[4][64];
    const int enc = blockIdx.y;
    const float* S  = enc ? S_P  : S_V;
    const float* bc = enc ? bc_p : bc_v;
    float* hout     = enc ? hp   : hv;
    const int b = blockIdx.x, tid = threadIdx.x;
    const int lane = tid & 63, wv = tid >> 6;
    const int n = lane & 31, kg = lane >> 5;

    {
        const float4* src = (const float4*)(S + (size_t)b * 3072);
        float4* dst = (float4*)xs;
        for (int i = tid; i < 768; i += 256) dst[i] = src[i];
    }
    if (tid < 64) bcs[tid] = bc[tid];
    __syncthreads();

    // build padded bf16 row table
    for (int t = tid; t < 1024; t += 256) {
        uint4 lo = make_uint4(0, 0, 0, 0), hi = make_uint4(0, 0, 0, 0);
        if (t < 1022) {
            const float* xp = xs + 3 * t;
            lo.x = pk2(xp[0], xp[1]); lo.y = pk2(xp[2], xp[3]);
            lo.z = pk2(xp[4], xp[5]); lo.w = pk2(xp[6], xp[7]);
            hi.x = pk2(xp[8], 0.f);
        }
        *(uint4*)(rows + t * 16)     = lo;
        *(uint4*)(rows + t * 16 + 8) = hi;
    }

    const bf16x8* fr = (const bf16x8*)Frag;
    bf16x8 Af0 = fr[(20 + enc * 2 + 0) * 64 + lane];
    bf16x8 Af1 = fr[(20 + enc * 2 + 1) * 64 + lane];
    __syncthreads();

    f32x16 cb0, cb1;
    #pragma unroll
    for (int r = 0; r < 16; ++r) {
        int crow = (r & 3) + 8 * (r >> 2) + 4 * kg;
        cb0[r] = bcs[crow];
        cb1[r] = bcs[32 + crow];
    }

    float h0[16], h1[16];
    #pragma unroll
    for (int r = 0; r < 16; ++r) { h0[r] = 0.f; h1[r] = 0.f; }

    #pragma unroll 1
    for (int nt = wv; nt < 32; nt += 4) {
        bf16x8 Bf = *(const bf16x8*)(rows + (nt * 32 + n) * 16 + kg * 8);
        f32x16 y0 = __builtin_amdgcn_mfma_f32_32x32x16_bf16(Af0, Bf, cb0, 0, 0, 0);
        f32x16 y1 = __builtin_amdgcn_mfma_f32_32x32x16_bf16(Af1, Bf, cb1, 0, 0, 0);
        #pragma unroll
        for (int r = 0; r < 16; ++r) {
            h0[r] += fmaxf(y0[r], 0.f);
            h1[r] += fmaxf(y1[r], 0.f);
        }
    }

    // sum over the 32 n-lanes (xor<=16 stays within each kg half)
    #pragma unroll
    for (int r = 0; r < 16; ++r) {
        float v = h0[r];
        v += __shfl_xor(v, 1);  v += __shfl_xor(v, 2);
        v += __shfl_xor(v, 4);  v += __shfl_xor(v, 8);
        v += __shfl_xor(v, 16);
        h0[r] = v;
        float u = h1[r];
        u += __shfl_xor(u, 1);  u += __shfl_xor(u, 2);
        u += __shfl_xor(u, 4);  u += __shfl_xor(u, 8);
        u += __shfl_xor(u, 16);
        h1[r] = u;
    }
    if (n == 0) {                       // lanes 0 (kg=0) and 32 (kg=1)
        #pragma unroll
        for (int r = 0; r < 16; ++r) {
            int crow = (r & 3) + 8 * (r >> 2) + 4 * kg;
            hpart[wv][crow]      = h0[r];
            hpart[wv][32 + crow] = h1[r];
        }
    }
    __syncthreads();
    if (tid < 64) {
        float s = hpart[0][tid] + hpart[1][tid] + hpart[2][tid] + hpart[3][tid];
        s -= 2.0f * fmaxf(bcs[tid], 0.f);       // remove the 2 zero-pad rows
        hout[(size_t)b * 64 + tid] = s * (1.0f / 1022.0f);
    }
}

// ---------------------------------------------------------------------------
// Physical model, both convs on MFMA.
// Phase 1 (32x32x16): rows[t][16] = bf16(x[3t..3t+14]) (K-util 15/16), bias
//   in C, maxpool4 across n-lanes, write p1T[tp][c] bf16 (stride 72).
//   rows chunked 2x512 to fit LDS (66 KB total -> 2 blocks/CU).
// Phase 2 (16x16x32): unchanged from R4 (verified): 5 shifted GEMMs over p1T.
// ---------------------------------------------------------------------------
#define P1TS 72
__global__ __launch_bounds__(256, 2) void phys_kernel(
    const float* __restrict__ S, const unsigned short* __restrict__ Frag,
    const float* __restrict__ b1, const float* __restrict__ b2,
    float* __restrict__ y30)
{
    __shared__ __align__(16) float xs[3072];
    __shared__ __align__(16) unsigned short rows[512 * 16];
    __shared__ __align__(16) unsigned short p1T[260 * P1TS];
    __shared__ float b1s[64];
    __shared__ float ypartL[4][32];
    const int b = blockIdx.x, tid = threadIdx.x;
    const int lane = tid & 63, wv = tid >> 6;
    const int n = lane & 31, kg = lane >> 5;

    {
        const float4* src = (const float4*)(S + (size_t)b * 3072);
        float4* dst = (float4*)xs;
        for (int i = tid; i < 768; i += 256) dst[i] = src[i];
    }
    if (tid < 64) b1s[tid] = b1[tid];
    // zero p1T rows 255..259 (read via kk shifts in phase 2)
    if (tid < 180) ((unsigned int*)(p1T + 255 * P1TS))[tid] = 0u;
    __syncthreads();

    const bf16x8* fr = (const bf16x8*)Frag;
    bf16x8 A10 = fr[24 * 64 + lane];
    bf16x8 A11 = fr[25 * 64 + lane];
    f32x16 cb0, cb1;
    #pragma unroll
    for (int r = 0; r < 16; ++r) {
        int crow = (r & 3) + 8 * (r >> 2) + 4 * kg;
        cb0[r] = b1s[crow];
        cb1[r] = b1s[32 + crow];
    }

    #pragma unroll 1
    for (int chunk = 0; chunk < 2; ++chunk) {
        const int tbase = chunk * 512;
        for (int tl = tid; tl < 512; tl += 256) {
            int t = tbase + tl;
            uint4 lo = make_uint4(0, 0, 0, 0), hi = make_uint4(0, 0, 0, 0);
            if (t < 1020) {
                const float* xp = xs + 3 * t;
                lo.x = pk2(xp[0],  xp[1]);  lo.y = pk2(xp[2],  xp[3]);
                lo.z = pk2(xp[4],  xp[5]);  lo.w = pk2(xp[6],  xp[7]);
                hi.x = pk2(xp[8],  xp[9]);  hi.y = pk2(xp[10], xp[11]);
                hi.z = pk2(xp[12], xp[13]); hi.w = pk2(xp[14], 0.f);
            }
            *(uint4*)(rows + tl * 16)     = lo;
            *(uint4*)(rows + tl * 16 + 8) = hi;
        }
        __syncthreads();

        #pragma unroll 1
        for (int ntl = wv; ntl < 16; ntl += 4) {
            const int t0 = tbase + ntl * 32;
            bf16x8 Bf = *(const bf16x8*)(rows + (ntl * 32 + n) * 16 + kg * 8);
            f32x16 y0 = __builtin_amdgcn_mfma_f32_32x32x16_bf16(A10, Bf, cb0, 0, 0, 0);
            f32x16 y1 = __builtin_amdgcn_mfma_f32_32x32x16_bf16(A11, Bf, cb1, 0, 0, 0);
            // maxpool4 across n, pack c-pairs, write p1T
            #pragma unroll
            for (int r = 0; r < 16; r += 2) {
                float v0 = y0[r],   u0 = y0[r + 1];
                float v1 = y1[r],   u1 = y1[r + 1];
                v0 = fmaxf(v0, __shfl_xor(v0, 1)); v0 = fmaxf(v0, __shfl_xor(v0, 2));
                u0 = fmaxf(u0, __shfl_xor(u0, 1)); u0 = fmaxf(u0, __shfl_xor(u0, 2));
                v1 = fmaxf(v1, __shfl_xor(v1, 1)); v1 = fmaxf(v1, __shfl_xor(v1, 2));
                u1 = fmaxf(u1, __shfl_xor(u1, 1)); u1 = fmaxf(u1, __shfl_xor(u1, 2));
                if ((n & 3) == 0) {
                    int tp = (t0 + n) >> 2;
                    if (tp < 255) {
                        int c = (r & 3) + 8 * (r >> 2) + 4 * kg;
                        *(unsigned int*)(p1T + tp * P1TS + c)      = pk2(v0, u0);
                        *(unsigned int*)(p1T + tp * P1TS + 32 + c) = pk2(v1, u1);
                    }
                }
            }
        }
        __syncthreads();
    }

    // ---- phase 2: 5 shifted 16x16x32 GEMMs over p1T (verified in R4) ----
    bf16x8 Af[20];
    #pragma unroll
    for (int e = 0; e < 20; ++e) Af[e] = fr[e * 64 + lane];
    const int m_ = lane & 15, kg16 = lane >> 4;
    f32x4 acc[4][2];
    #pragma unroll
    for (int q = 0; q < 4; ++q) {
        acc[q][0] = (f32x4){0.f, 0.f, 0.f, 0.f};
        acc[q][1] = (f32x4){0.f, 0.f, 0.f, 0.f};
    }
    #pragma unroll
    for (int kk = 0; kk < 5; ++kk) {
        #pragma unroll
        for (int Ks = 0; Ks < 2; ++Ks) {
            const int e0 = (kk * 2 + Ks) * 2;
            #pragma unroll
            for (int q = 0; q < 4; ++q) {
                const int row = wv * 64 + q * 16 + m_ + kk;
                const bf16x8 Bf = *(const bf16x8*)(p1T + row * P1TS + Ks * 32 + kg16 * 8);
                acc[q][0] = __builtin_amdgcn_mfma_f32_16x16x32_bf16(
                    Af[e0], Bf, acc[q][0], 0, 0, 0);
                acc[q][1] = __builtin_amdgcn_mfma_f32_16x16x32_bf16(
                    Af[e0 + 1], Bf, acc[q][1], 0, 0, 0);
            }
        }
    }
    float ysum[2][4];
    #pragma unroll
    for (int t = 0; t < 2; ++t)
        #pragma unroll
        for (int r = 0; r < 4; ++r) ysum[t][r] = 0.f;
    #pragma unroll
    for (int q = 0; q < 4; ++q) {
        const int n0 = wv * 64 + q * 16 + m_;
        #pragma unroll
        for (int t = 0; t < 2; ++t) {
            #pragma unroll
            for (int r = 0; r < 4; ++r) {
                float v = acc[q][t][r];
                v = fmaxf(v, __shfl_xor(v, 1));
                v = fmaxf(v, __shfl_xor(v, 2));
                v = (((m_ & 3) == 0) && (n0 < 248)) ? v : 0.f;
                v += __shfl_xor(v, 4);
                v += __shfl_xor(v, 8);
                ysum[t][r] += v;
            }
        }
    }
    if (m_ == 0) {
        #pragma unroll
        for (int t = 0; t < 2; ++t)
            #pragma unroll
            for (int r = 0; r < 4; ++r)
                ypartL[wv][t * 16 + kg16 * 4 + r] = ysum[t][r];
    }
    __syncthreads();
    if (tid < 30) {
        float y = (ypartL[0][tid] + ypartL[1][tid] +
                   ypartL[2][tid] + ypartL[3][tid]) * (1.0f / 62.0f) + b2[tid];
        y30[(size_t)b * 30 + tid] = y;
    }
}

// ---------------------------------------------------------------------------
// Heads + LSE soft-OR fusion + masked 4-token attention. 1 wave per b.
// ---------------------------------------------------------------------------
__global__ __launch_bounds__(64) void head_kernel(
    const int* __restrict__ pairs,
    const float* __restrict__ hv_g, const float* __restrict__ hp_g,
    const float* __restrict__ y30_g,
    const float* __restrict__ Ws_v, const float* __restrict__ bs_v,
    const float* __restrict__ Wd_v, const float* __restrict__ bd_v,
    const float* __restrict__ Ws_p, const float* __restrict__ bs_p,
    const float* __restrict__ Wd_p, const float* __restrict__ bd_p,
    const float* __restrict__ Wsp, const float* __restrict__ bsp,
    const float* __restrict__ Wa,  const float* __restrict__ ba,
    const float* __restrict__ Wf,  const float* __restrict__ bf,
    float* __restrict__ out)
{
    __shared__ float hv[64], hp[64];
    __shared__ float s0v[32], s0p[32];
    __shared__ float f4[4][32];
    __shared__ float qk[4][192];
    __shared__ float qm[32];
    __shared__ float lg[4][4];
    __shared__ float wsm[4][4];
    __shared__ float ffl[4][32];
    const int b = blockIdx.x;
    const int lane = threadIdx.x;
    const int pf = pairs[b];

    hv[lane] = hv_g[(size_t)b * 64 + lane];
    hp[lane] = hp_g[(size_t)b * 64 + lane];
    __syncthreads();

    if (lane < 30) {
        float a_s = bs_v[lane], a_d = bd_v[lane];
        float p_s = bs_p[lane], p_d = bd_p[lane];
        for (int k = 0; k < 64; ++k) {
            float h = hv[k], g = hp[k];
            a_s = fmaf(h, Ws_v[k*30 + lane], a_s);
            a_d = fmaf(h, Wd_v[k*30 + lane], a_d);
            p_s = fmaf(g, Ws_p[k*30 + lane], p_s);
            p_d = fmaf(g, Wd_p[k*30 + lane], p_d);
        }
        s0v[lane] = a_s;
        s0p[lane] = p_s;
        f4[3][lane] = a_d;
        f4[0][lane] = p_d;
        f4[2][lane] = y30_g[(size_t)b * 30 + lane];
    }
    __syncthreads();

    if (lane < 30) {
        float v_s = bsp[lane], p_s = bsp[lane];
        for (int j = 0; j < 30; ++j) {
            float wj = Wsp[j*30 + lane];
            v_s = fmaf(s0v[j], wj, v_s);
            p_s = fmaf(s0p[j], wj, p_s);
        }
        float h1 = v_s, h2 = p_s, h12 = h1 + h2;
        float m1 = fmaxf(h12, fmaxf(h1, h2));
        float lse1 = m1 + logf(2.f*expf(h12 - m1) + expf(h1 - m1) + expf(h2 - m1));
        float m2 = fmaxf(0.f, fmaxf(h1, h2));
        float lse2 = m2 + logf(2.f*expf(-m2) + expf(h1 - m2) + expf(h2 - m2));
        f4[1][lane] = pf ? (lse1 - lse2) : h2;
    }
    __syncthreads();

    #pragma unroll 1
    for (int t = 0; t < 4; ++t) {
        #pragma unroll 1
        for (int c0 = 0; c0 < 3; ++c0) {
            int c = c0 * 64 + lane;
            float a = ba[c];
            for (int j = 0; j < 30; ++j)
                a = fmaf(f4[t][j], Wa[j*192 + c], a);
            qk[t][c] = a;
        }
    }
    __syncthreads();

    if (lane < 32) {
        float q0 = qk[0][lane], q1 = qk[1][lane], q2 = qk[2][lane], q3 = qk[3][lane];
        qm[lane] = pf ? (q0 + q1 + q2 + q3) * 0.25f
                      : (q0 + q1 + q2) * (1.f / 3.f);
    }
    __syncthreads();

    if (lane < 16) {
        int n = lane >> 2, t = lane & 3;
        float a = 0.f;
        const float* kp = &qk[t][64 + 32*n];
        for (int d = 0; d < 32; ++d) a = fmaf(kp[d], qm[d], a);
        a *= 0.17677669529663687f;
        if (t == 3 && pf == 0) a = -INFINITY;
        lg[n][t] = a;
    }
    __syncthreads();

    if (lane < 4) {
        float l0 = lg[lane][0], l1 = lg[lane][1], l2 = lg[lane][2], l3 = lg[lane][3];
        float m = fmaxf(fmaxf(l0, l1), fmaxf(l2, l3));
        float e0 = expf(l0 - m), e1 = expf(l1 - m), e2 = expf(l2 - m);
        float e3 = expf(l3 - m);
        float s = e0 + e1 + e2 + e3;
        wsm[lane][0] = e0 / s; wsm[lane][1] = e1 / s;
        wsm[lane][2] = e2 / s; wsm[lane][3] = e3 / s;
    }
    __syncthreads();

    #pragma unroll
    for (int r = 0; r < 2; ++r) {
        int n = (lane >> 5) + 2 * r, d = lane & 31;
        float a = 0.f;
        #pragma unroll
        for (int t = 0; t < 4; ++t) a = fmaf(wsm[n][t], qk[t][32 + d], a);
        ffl[n][d] = a;
    }
    __syncthreads();

    if (lane < 4) {
        float a = bf[lane];
        for (int d = 0; d < 32; ++d) a = fmaf(ffl[lane][d], Wf[d*4 + lane], a);
        out[(size_t)b * 4 + lane] = a;
    }
}

// ---------------------------------------------------------------------------
extern "C" void kernel_launch(void* const* d_in, const int* in_sizes, int n_in,
                              void* d_out, int out_size, void* d_ws, size_t ws_size,
                              hipStream_t stream)
{
    const int*   pairs = (const int*)  d_in[0];
    const float* S_V   = (const float*)d_in[1];
    const float* S_P   = (const float*)d_in[2];
    const float* S_P1  = (const float*)d_in[3];
    const float* Wc_v  = (const float*)d_in[4];
    const float* bc_v  = (const float*)d_in[5];
    const float* Ws_v  = (const float*)d_in[6];
    const float* bs_v  = (const float*)d_in[7];
    const float* Wd_v  = (const float*)d_in[8];
    const float* bd_v  = (const float*)d_in[9];
    const float* Wc_p  = (const float*)d_in[10];
    const float* bc_p  = (const float*)d_in[11];
    const float* Ws_p  = (const float*)d_in[12];
    const float* bs_p  = (const float*)d_in[13];
    const float* Wd_p  = (const float*)d_in[14];
    const float* bd_p  = (const float*)d_in[15];
    const float* Wsp   = (const float*)d_in[16];
    const float* bsp   = (const float*)d_in[17];
    const float* W1    = (const float*)d_in[18];
    const float* b1    = (const float*)d_in[19];
    const float* W2    = (const float*)d_in[20];
    const float* b2    = (const float*)d_in[21];
    const float* Wa    = (const float*)d_in[22];
    const float* ba    = (const float*)d_in[23];
    const float* Wf    = (const float*)d_in[24];
    const float* bf    = (const float*)d_in[25];
    float* out = (float*)d_out;

    // ws: h_v[B][64] | h_p[B][64] | y30[B][30] | frags (26 x 64 x 16B)
    float* ws  = (float*)d_ws;
    float* h_v = ws;
    float* h_p = ws + (size_t)B_ * 64;
    float* y30 = ws + (size_t)2 * B_ * 64;
    unsigned short* Frag = (unsigned short*)(ws + (size_t)2 * B_ * 64 + (size_t)B_ * 30);

    prep_frags<<<7, 256, 0, stream>>>(W2, Wc_v, Wc_p, W1, Frag);
    encode_mfma_kernel<<<dim3(B_, 2), 256, 0, stream>>>(
        S_V, S_P, Frag, bc_v, bc_p, h_v, h_p);
    phys_kernel<<<B_, 256, 0, stream>>>(S_P1, Frag, b1, b2, y30);
    head_kernel<<<B_, 64, 0, stream>>>(pairs, h_v, h_p, y30,
                                       Ws_v, bs_v, Wd_v, bd_v,
                                       Ws_p, bs_p, Wd_p, bd_p,
                                       Wsp, bsp, Wa, ba, Wf, bf, out);
}

// Round 6
// 400.831 us; speedup vs baseline: 3.7758x; 1.1666x over previous
//
#include <hip/hip_runtime.h>
#include <math.h>

#define B_   4096

typedef __attribute__((ext_vector_type(8)))  short bf16x8;   // 8 bf16 = 4 VGPR
typedef __attribute__((ext_vector_type(4)))  float f32x4;
typedef __attribute__((ext_vector_type(16))) float f32x16;

__device__ __forceinline__ unsigned short f2bf(float f) {   // RNE f32->bf16
    unsigned int u = __float_as_uint(f);
    u += 0x7FFFu + ((u >> 16) & 1u);
    return (unsigned short)(u >> 16);
}
__device__ __forceinline__ unsigned int pk2(float a, float b) {
    return (unsigned int)f2bf(a) | ((unsigned int)f2bf(b) << 16);
}
__device__ __forceinline__ f32x16 zero16() {
    f32x16 z;
    #pragma unroll
    for (int i = 0; i < 16; ++i) z[i] = 0.f;
    return z;
}
// quad all-reduce max via DPP (VALU only, no LDS pipe). All lanes active.
__device__ __forceinline__ float maxq(float v) {
    int y1 = __builtin_amdgcn_update_dpp(0, __float_as_int(v), 0xB1, 0xF, 0xF, true); // xor1
    float v1 = fmaxf(v, __int_as_float(y1));
    int y2 = __builtin_amdgcn_update_dpp(0, __float_as_int(v1), 0x4E, 0xF, 0xF, true); // xor2
    return fmaxf(v1, __int_as_float(y2));
}

// ---------------------------------------------------------------------------
// prep: all MFMA A-fragments (26 x 64 lanes x 16B). Bias folded at k=15 for
// the 32x32x16 conv fragments (B supplies a ones-column there).
//  e 0..19 : phys phase-2 (16x16x32), e=(kk*2+Ks)*2+ftile
//  e 20..23: encoder conv (32x32x16), e-20=enc*2+mt; j<9 W, j==15 bias
//  e 24..25: phys phase-1 (32x32x16), mt=e-24;       j<15 W, j==15 bias
// ---------------------------------------------------------------------------
__global__ void prep_frags(const float* __restrict__ W2,
                           const float* __restrict__ Wc_v,
                           const float* __restrict__ Wc_p,
                           const float* __restrict__ W1,
                           const float* __restrict__ bc_v,
                           const float* __restrict__ bc_p,
                           const float* __restrict__ b1,
                           unsigned short* __restrict__ ws_frag)
{
    int gid = blockIdx.x * 256 + threadIdx.x;
    if (gid >= 26 * 64) return;
    int lane = gid & 63, e = gid >> 6;
    unsigned int w[4];
    if (e < 20) {
        int ft = e & 1, Ks = (e >> 1) & 1, kk = e >> 2;
        int m = lane & 15, kg = lane >> 4;
        int f = ft * 16 + m;
        #pragma unroll
        for (int p = 0; p < 4; ++p) {
            int i0 = Ks * 32 + kg * 8 + 2 * p;
            float v0 = (f < 30) ? W2[f * 320 + i0 * 5 + kk] : 0.f;
            float v1 = (f < 30) ? W2[f * 320 + (i0 + 1) * 5 + kk] : 0.f;
            w[p] = pk2(v0, v1);
        }
    } else if (e < 24) {
        int e2 = e - 20, enc = e2 >> 1, mt = e2 & 1;
        const float* Wc = enc ? Wc_p : Wc_v;
        const float* bc = enc ? bc_p : bc_v;
        int c = mt * 32 + (lane & 31), kg = lane >> 5;
        #pragma unroll
        for (int p = 0; p < 4; ++p) {
            int j0 = kg * 8 + 2 * p, j1 = j0 + 1;
            float v0 = (j0 < 9) ? Wc[c * 9 + (j0 % 3) * 3 + (j0 / 3)] : 0.f;
            float v1 = (j1 < 9) ? Wc[c * 9 + (j1 % 3) * 3 + (j1 / 3)]
                                : (j1 == 15 ? bc[c] : 0.f);
            w[p] = pk2(v0, v1);
        }
    } else {
        int mt = e - 24;
        int c = mt * 32 + (lane & 31), kg = lane >> 5;
        #pragma unroll
        for (int p = 0; p < 4; ++p) {
            int j0 = kg * 8 + 2 * p, j1 = j0 + 1;
            float v0 = (j0 < 15) ? W1[c * 15 + (j0 % 3) * 5 + (j0 / 3)] : 0.f;
            float v1 = (j1 < 15) ? W1[c * 15 + (j1 % 3) * 5 + (j1 / 3)]
                                 : (j1 == 15 ? b1[c] : 0.f);
            w[p] = pk2(v0, v1);
        }
    }
    ((uint4*)ws_frag)[gid] = make_uint4(w[0], w[1], w[2], w[3]);
}

// ---------------------------------------------------------------------------
// Encoder: conv(3->64,K=3)+bias (in-K) + ReLU + mean, all via 32x32x16 MFMA.
// B built per-lane straight from global (VMEM pipe; no LDS staging at all).
// Lane-sum via one LDS transpose (hmat) instead of shuffle butterflies.
// ---------------------------------------------------------------------------
__global__ __launch_bounds__(256, 4) void encode_mfma_kernel(
    const float* __restrict__ S_V, const float* __restrict__ S_P,
    const unsigned short* __restrict__ Frag,
    float* __restrict__ hv, float* __restrict__ hp)
{
    __shared__ __align__(16) float hmat[4 * 32 * 68];   // 34.8 KB
    const int enc = blockIdx.y;
    const float* __restrict__ S = enc ? S_P : S_V;
    float* hout = enc ? hp : hv;
    const int b = blockIdx.x, tid = threadIdx.x;
    const int lane = tid & 63, wv = tid >> 6;
    const int n = lane & 31, kg = lane >> 5;
    const float* __restrict__ xb = S + (size_t)b * 3072;

    const bf16x8* fr = (const bf16x8*)Frag;
    bf16x8 Af0 = fr[(20 + enc * 2) * 64 + lane];
    bf16x8 Af1 = fr[(21 + enc * 2) * 64 + lane];

    float h0[16], h1[16];
    #pragma unroll
    for (int r = 0; r < 16; ++r) { h0[r] = 0.f; h1[r] = 0.f; }

    #pragma unroll 1
    for (int nt = wv; nt < 32; nt += 4) {
        const int t = nt * 32 + n;
        union { unsigned int u[4]; bf16x8 v; } bb;
        bb.u[0] = bb.u[1] = bb.u[2] = bb.u[3] = 0u;
        if (t < 1022) {
            const float* xp = xb + 3 * t;
            if (kg == 0) {          // k=0..7 -> x[3t..3t+7]
                bb.u[0] = pk2(xp[0], xp[1]); bb.u[1] = pk2(xp[2], xp[3]);
                bb.u[2] = pk2(xp[4], xp[5]); bb.u[3] = pk2(xp[6], xp[7]);
            } else {                // k=8 -> x[3t+8]; k=15 -> 1.0 (bias col)
                bb.u[0] = pk2(xp[8], 0.f);
                bb.u[3] = pk2(0.f, 1.0f);
            }
        }
        f32x16 z = zero16();
        f32x16 y0 = __builtin_amdgcn_mfma_f32_32x32x16_bf16(Af0, bb.v, z, 0, 0, 0);
        f32x16 y1 = __builtin_amdgcn_mfma_f32_32x32x16_bf16(Af1, bb.v, z, 0, 0, 0);
        #pragma unroll
        for (int r = 0; r < 16; ++r) {
            h0[r] += fmaxf(y0[r], 0.f);
            h1[r] += fmaxf(y1[r], 0.f);
        }
    }

    // transpose to LDS: c = (r&3) + 8*(r>>2) + 4*kg  (+32 for h1)
    float* hm = hmat + (wv * 32 + n) * 68;
    #pragma unroll
    for (int g4 = 0; g4 < 4; ++g4) {
        int c0 = g4 * 8 + 4 * kg;
        *(float4*)(hm + c0)      = make_float4(h0[4*g4+0], h0[4*g4+1], h0[4*g4+2], h0[4*g4+3]);
        *(float4*)(hm + c0 + 32) = make_float4(h1[4*g4+0], h1[4*g4+1], h1[4*g4+2], h1[4*g4+3]);
    }
    __syncthreads();
    if (tid < 64) {                 // lane = channel c; 2-way banks (free)
        float s = 0.f;
        #pragma unroll 8
        for (int gn = 0; gn < 128; ++gn) s += hmat[gn * 68 + tid];
        hout[(size_t)b * 64 + tid] = s * (1.0f / 1022.0f);
    }
}

// ---------------------------------------------------------------------------
// Physical model. Phase 1: conv(3->64,K=5)+bias(in-K) via 32x32x16 MFMA with
// per-lane global B; maxpool4 via DPP quad-max; survivors write bf16 p1T.
// Phase 2: 5 shifted 16x16x32 GEMMs over p1T (Ks-outer: 10 live A-frags).
// Epilogue: DPP quad-max pool -> ymat (overlaid on dead p1T) -> strided sum.
// ---------------------------------------------------------------------------
#define P1TS 72
__global__ __launch_bounds__(256, 4) void phys_kernel(
    const float* __restrict__ S, const unsigned short* __restrict__ Frag,
    const float* __restrict__ b2, float* __restrict__ y30)
{
    __shared__ __align__(16) unsigned short p1T[260 * P1TS];   // 37.4 KB
    float* ymat = (float*)p1T;                                  // overlay, phase-2 epilogue
    const int b = blockIdx.x, tid = threadIdx.x;
    const int lane = tid & 63, wv = tid >> 6;
    const float* __restrict__ xb = S + (size_t)b * 3072;
    const bf16x8* fr = (const bf16x8*)Frag;

    // zero pad rows tp=255..259 (read via kk shifts in phase 2)
    if (tid < 180) ((unsigned int*)(p1T + 255 * P1TS))[tid] = 0u;

    // ---- phase 1 ----
    {
        const int n = lane & 31, kg2 = lane >> 5;
        bf16x8 A10 = fr[24 * 64 + lane];
        bf16x8 A11 = fr[25 * 64 + lane];
        #pragma unroll 1
        for (int ntl = wv; ntl < 32; ntl += 4) {
            const int t = ntl * 32 + n;
            union { unsigned int u[4]; bf16x8 v; } bb;
            bb.u[0] = bb.u[1] = bb.u[2] = bb.u[3] = 0u;
            if (t < 1020) {
                const float* xp = xb + 3 * t + kg2 * 8;
                if (kg2 == 0) {     // k=0..7
                    bb.u[0] = pk2(xp[0], xp[1]); bb.u[1] = pk2(xp[2], xp[3]);
                    bb.u[2] = pk2(xp[4], xp[5]); bb.u[3] = pk2(xp[6], xp[7]);
                } else {            // k=8..14 -> x, k=15 -> 1.0 (bias col)
                    bb.u[0] = pk2(xp[0], xp[1]); bb.u[1] = pk2(xp[2], xp[3]);
                    bb.u[2] = pk2(xp[4], xp[5]); bb.u[3] = pk2(xp[6], 1.0f);
                }
            }
            f32x16 z = zero16();
            f32x16 y0 = __builtin_amdgcn_mfma_f32_32x32x16_bf16(A10, bb.v, z, 0, 0, 0);
            f32x16 y1 = __builtin_amdgcn_mfma_f32_32x32x16_bf16(A11, bb.v, z, 0, 0, 0);
            const int t4 = t >> 2;
            #pragma unroll
            for (int g4 = 0; g4 < 4; ++g4) {
                float a0 = maxq(y0[4*g4+0]), a1 = maxq(y0[4*g4+1]);
                float a2 = maxq(y0[4*g4+2]), a3 = maxq(y0[4*g4+3]);
                float c0v = maxq(y1[4*g4+0]), c1v = maxq(y1[4*g4+1]);
                float c2v = maxq(y1[4*g4+2]), c3v = maxq(y1[4*g4+3]);
                if ((n & 3) == 0 && t4 < 255) {
                    int c0 = g4 * 8 + 4 * kg2;
                    unsigned int* d0 = (unsigned int*)(p1T + t4 * P1TS + c0);
                    d0[0] = pk2(a0, a1); d0[1] = pk2(a2, a3);
                    unsigned int* d1 = (unsigned int*)(p1T + t4 * P1TS + c0 + 32);
                    d1[0] = pk2(c0v, c1v); d1[1] = pk2(c2v, c3v);
                }
            }
        }
    }
    __syncthreads();

    // ---- phase 2 ----
    const int m_ = lane & 15, kg16 = lane >> 4;
    f32x4 acc[4][2];
    #pragma unroll
    for (int q = 0; q < 4; ++q) {
        acc[q][0] = (f32x4){0.f, 0.f, 0.f, 0.f};
        acc[q][1] = (f32x4){0.f, 0.f, 0.f, 0.f};
    }
    #pragma unroll 1
    for (int Ks = 0; Ks < 2; ++Ks) {
        bf16x8 Af[10];
        #pragma unroll
        for (int kk = 0; kk < 5; ++kk) {
            Af[kk * 2]     = fr[((kk * 2 + Ks) * 2) * 64 + lane];
            Af[kk * 2 + 1] = fr[((kk * 2 + Ks) * 2 + 1) * 64 + lane];
        }
        #pragma unroll
        for (int kk = 0; kk < 5; ++kk) {
            #pragma unroll
            for (int q = 0; q < 4; ++q) {
                const int row = wv * 64 + q * 16 + m_ + kk;
                const bf16x8 Bf = *(const bf16x8*)(p1T + row * P1TS + Ks * 32 + kg16 * 8);
                acc[q][0] = __builtin_amdgcn_mfma_f32_16x16x32_bf16(Af[kk*2],   Bf, acc[q][0], 0, 0, 0);
                acc[q][1] = __builtin_amdgcn_mfma_f32_16x16x32_bf16(Af[kk*2+1], Bf, acc[q][1], 0, 0, 0);
            }
        }
    }
    __syncthreads();    // all p1T reads done; safe to overlay ymat

    // epilogue: pool4 over t2 (m_ quads) then write ymat[n4][36]
    #pragma unroll
    for (int q = 0; q < 4; ++q) {
        #pragma unroll
        for (int tt = 0; tt < 2; ++tt) {
            float p0 = maxq(acc[q][tt][0]);
            float p1 = maxq(acc[q][tt][1]);
            float p2 = maxq(acc[q][tt][2]);
            float p3 = maxq(acc[q][tt][3]);
            if ((m_ & 3) == 0) {
                int n4 = wv * 16 + q * 4 + (m_ >> 2);
                int f0 = tt * 16 + kg16 * 4;
                *(float4*)(ymat + n4 * 36 + f0) = make_float4(p0, p1, p2, p3);
            }
        }
    }
    __syncthreads();
    if (tid < 30) {
        float s = 0.f;
        #pragma unroll 2
        for (int w = 0; w < 62; ++w) s += ymat[w * 36 + tid];
        y30[(size_t)b * 30 + tid] = s * (1.0f / 62.0f) + b2[tid];
    }
}

// ---------------------------------------------------------------------------
// Heads + LSE soft-OR fusion + masked 4-token attention. 1 wave per b.
// (unchanged from R4/R5 — verified)
// ---------------------------------------------------------------------------
__global__ __launch_bounds__(64) void head_kernel(
    const int* __restrict__ pairs,
    const float* __restrict__ hv_g, const float* __restrict__ hp_g,
    const float* __restrict__ y30_g,
    const float* __restrict__ Ws_v, const float* __restrict__ bs_v,
    const float* __restrict__ Wd_v, const float* __restrict__ bd_v,
    const float* __restrict__ Ws_p, const float* __restrict__ bs_p,
    const float* __restrict__ Wd_p, const float* __restrict__ bd_p,
    const float* __restrict__ Wsp, const float* __restrict__ bsp,
    const float* __restrict__ Wa,  const float* __restrict__ ba,
    const float* __restrict__ Wf,  const float* __restrict__ bf,
    float* __restrict__ out)
{
    __shared__ float hv[64], hp[64];
    __shared__ float s0v[32], s0p[32];
    __shared__ float f4[4][32];
    __shared__ float qk[4][192];
    __shared__ float qm[32];
    __shared__ float lg[4][4];
    __shared__ float wsm[4][4];
    __shared__ float ffl[4][32];
    const int b = blockIdx.x;
    const int lane = threadIdx.x;
    const int pf = pairs[b];

    hv[lane] = hv_g[(size_t)b * 64 + lane];
    hp[lane] = hp_g[(size_t)b * 64 + lane];
    __syncthreads();

    if (lane < 30) {
        float a_s = bs_v[lane], a_d = bd_v[lane];
        float p_s = bs_p[lane], p_d = bd_p[lane];
        for (int k = 0; k < 64; ++k) {
            float h = hv[k], g = hp[k];
            a_s = fmaf(h, Ws_v[k*30 + lane], a_s);
            a_d = fmaf(h, Wd_v[k*30 + lane], a_d);
            p_s = fmaf(g, Ws_p[k*30 + lane], p_s);
            p_d = fmaf(g, Wd_p[k*30 + lane], p_d);
        }
        s0v[lane] = a_s;
        s0p[lane] = p_s;
        f4[3][lane] = a_d;
        f4[0][lane] = p_d;
        f4[2][lane] = y30_g[(size_t)b * 30 + lane];
    }
    __syncthreads();

    if (lane < 30) {
        float v_s = bsp[lane], p_s = bsp[lane];
        for (int j = 0; j < 30; ++j) {
            float wj = Wsp[j*30 + lane];
            v_s = fmaf(s0v[j], wj, v_s);
            p_s = fmaf(s0p[j], wj, p_s);
        }
        float h1 = v_s, h2 = p_s, h12 = h1 + h2;
        float m1 = fmaxf(h12, fmaxf(h1, h2));
        float lse1 = m1 + logf(2.f*expf(h12 - m1) + expf(h1 - m1) + expf(h2 - m1));
        float m2 = fmaxf(0.f, fmaxf(h1, h2));
        float lse2 = m2 + logf(2.f*expf(-m2) + expf(h1 - m2) + expf(h2 - m2));
        f4[1][lane] = pf ? (lse1 - lse2) : h2;
    }
    __syncthreads();

    #pragma unroll 1
    for (int t = 0; t < 4; ++t) {
        #pragma unroll 1
        for (int c0 = 0; c0 < 3; ++c0) {
            int c = c0 * 64 + lane;
            float a = ba[c];
            for (int j = 0; j < 30; ++j)
                a = fmaf(f4[t][j], Wa[j*192 + c], a);
            qk[t][c] = a;
        }
    }
    __syncthreads();

    if (lane < 32) {
        float q0 = qk[0][lane], q1 = qk[1][lane], q2 = qk[2][lane], q3 = qk[3][lane];
        qm[lane] = pf ? (q0 + q1 + q2 + q3) * 0.25f
                      : (q0 + q1 + q2) * (1.f / 3.f);
    }
    __syncthreads();

    if (lane < 16) {
        int n = lane >> 2, t = lane & 3;
        float a = 0.f;
        const float* kp = &qk[t][64 + 32*n];
        for (int d = 0; d < 32; ++d) a = fmaf(kp[d], qm[d], a);
        a *= 0.17677669529663687f;
        if (t == 3 && pf == 0) a = -INFINITY;
        lg[n][t] = a;
    }
    __syncthreads();

    if (lane < 4) {
        float l0 = lg[lane][0], l1 = lg[lane][1], l2 = lg[lane][2], l3 = lg[lane][3];
        float m = fmaxf(fmaxf(l0, l1), fmaxf(l2, l3));
        float e0 = expf(l0 - m), e1 = expf(l1 - m), e2 = expf(l2 - m);
        float e3 = expf(l3 - m);
        float s = e0 + e1 + e2 + e3;
        wsm[lane][0] = e0 / s; wsm[lane][1] = e1 / s;
        wsm[lane][2] = e2 / s; wsm[lane][3] = e3 / s;
    }
    __syncthreads();

    #pragma unroll
    for (int r = 0; r < 2; ++r) {
        int n = (lane >> 5) + 2 * r, d = lane & 31;
        float a = 0.f;
        #pragma unroll
        for (int t = 0; t < 4; ++t) a = fmaf(wsm[n][t], qk[t][32 + d], a);
        ffl[n][d] = a;
    }
    __syncthreads();

    if (lane < 4) {
        float a = bf[lane];
        for (int d = 0; d < 32; ++d) a = fmaf(ffl[lane][d], Wf[d*4 + lane], a);
        out[(size_t)b * 4 + lane] = a;
    }
}

// ---------------------------------------------------------------------------
extern "C" void kernel_launch(void* const* d_in, const int* in_sizes, int n_in,
                              void* d_out, int out_size, void* d_ws, size_t ws_size,
                              hipStream_t stream)
{
    const int*   pairs = (const int*)  d_in[0];
    const float* S_V   = (const float*)d_in[1];
    const float* S_P   = (const float*)d_in[2];
    const float* S_P1  = (const float*)d_in[3];
    const float* Wc_v  = (const float*)d_in[4];
    const float* bc_v  = (const float*)d_in[5];
    const float* Ws_v  = (const float*)d_in[6];
    const float* bs_v  = (const float*)d_in[7];
    const float* Wd_v  = (const float*)d_in[8];
    const float* bd_v  = (const float*)d_in[9];
    const float* Wc_p  = (const float*)d_in[10];
    const float* bc_p  = (const float*)d_in[11];
    const float* Ws_p  = (const float*)d_in[12];
    const float* bs_p  = (const float*)d_in[13];
    const float* Wd_p  = (const float*)d_in[14];
    const float* bd_p  = (const float*)d_in[15];
    const float* Wsp   = (const float*)d_in[16];
    const float* bsp   = (const float*)d_in[17];
    const float* W1    = (const float*)d_in[18];
    const float* b1    = (const float*)d_in[19];
    const float* W2    = (const float*)d_in[20];
    const float* b2    = (const float*)d_in[21];
    const float* Wa    = (const float*)d_in[22];
    const float* ba    = (const float*)d_in[23];
    const float* Wf    = (const float*)d_in[24];
    const float* bf    = (const float*)d_in[25];
    float* out = (float*)d_out;

    // ws: h_v[B][64] | h_p[B][64] | y30[B][30] | frags (26 x 64 x 16B)
    float* ws  = (float*)d_ws;
    float* h_v = ws;
    float* h_p = ws + (size_t)B_ * 64;
    float* y30 = ws + (size_t)2 * B_ * 64;
    unsigned short* Frag = (unsigned short*)(ws + (size_t)2 * B_ * 64 + (size_t)B_ * 30);

    prep_frags<<<7, 256, 0, stream>>>(W2, Wc_v, Wc_p, W1, bc_v, bc_p, b1, Frag);
    encode_mfma_kernel<<<dim3(B_, 2), 256, 0, stream>>>(
        S_V, S_P, Frag, h_v, h_p);
    phys_kernel<<<B_, 256, 0, stream>>>(S_P1, Frag, b2, y30);
    head_kernel<<<B_, 64, 0, stream>>>(pairs, h_v, h_p, y30,
                                       Ws_v, bs_v, Wd_v, bd_v,
                                       Ws_p, bs_p, Wd_p, bd_p,
                                       Wsp, bsp, Wa, ba, Wf, bf, out);
}